// Round 2
// baseline (709.102 us; speedup 1.0000x reference)
//
#include <hip/hip_runtime.h>

// ---------------------------------------------------------------------------
// Motion_Grid: PE(sin/cos @ 3 freqs) -> 6 trilinear samples (3 grids) -> MLP
// Round 2: spatial bucket-sort of points (locality for the grid2 gathers) +
//          fused x-corner-pair loads (48 -> 24 gathers/pt).
// ---------------------------------------------------------------------------

#define NBINS 32768   // 32^3 buckets over the 128^3 grid2 sin-sample space

// Pack grid + noise into (D,H,W,C) layout so one corner-pair = contiguous bytes.
template<int C>
__global__ __launch_bounds__(256)
void pack_grid_k(const float* __restrict__ g, const float* __restrict__ nz,
                 float* __restrict__ out, int nvox) {
    int v = blockIdx.x * 256 + threadIdx.x;
    if (v >= nvox) return;
    float vals[C];
#pragma unroll
    for (int c = 0; c < C; ++c) vals[c] = g[c * nvox + v] + nz[c * nvox + v];
#pragma unroll
    for (int c = 0; c < C; ++c) out[v * C + c] = vals[c];
}

// Bucket key from the grid2 sin-sample voxel, 4^3-voxel buckets.
__global__ __launch_bounds__(256)
void hist_k(const float* __restrict__ x, int* __restrict__ keys,
            int* __restrict__ hist, int npts) {
    int p = blockIdx.x * 256 + threadIdx.x;
    if (p >= npts) return;
    float xv = x[3 * p + 0], yv = x[3 * p + 1], zv = x[3 * p + 2];
    // sin(4*pi*t) = hw_sin(2*t) (hw trig takes revolutions)
    float sx = __builtin_amdgcn_sinf(2.f * xv);
    float sy = __builtin_amdgcn_sinf(2.f * yv);
    float sz = __builtin_amdgcn_sinf(2.f * zv);
    int ix = (int)floorf(fmaf(sx, 64.f, 63.5f)); ix = min(max(ix, 0), 127);
    int iy = (int)floorf(fmaf(sy, 64.f, 63.5f)); iy = min(max(iy, 0), 127);
    int iz = (int)floorf(fmaf(sz, 64.f, 63.5f)); iz = min(max(iz, 0), 127);
    int key = ((iz >> 2) << 10) | ((iy >> 2) << 5) | (ix >> 2);
    keys[p] = key;
    atomicAdd(&hist[key], 1);
}

// Exclusive prefix sum over NBINS bins; single block.
__global__ __launch_bounds__(256)
void scan_k(const int* __restrict__ hist, int* __restrict__ offs) {
    __shared__ int partial[256];
    const int PER = NBINS / 256;  // 128
    int tid = threadIdx.x;
    int base = tid * PER;
    int s = 0;
    for (int i = 0; i < PER; ++i) s += hist[base + i];
    partial[tid] = s;
    __syncthreads();
    if (tid == 0) {
        int acc = 0;
        for (int j = 0; j < 256; ++j) { int t = partial[j]; partial[j] = acc; acc += t; }
    }
    __syncthreads();
    int run = partial[tid];
    for (int i = 0; i < PER; ++i) { offs[base + i] = run; run += hist[base + i]; }
}

__global__ __launch_bounds__(256)
void scatter_k(const float* __restrict__ x, const int* __restrict__ keys,
               int* __restrict__ offs, float4* __restrict__ sorted, int npts) {
    int p = blockIdx.x * 256 + threadIdx.x;
    if (p >= npts) return;
    int k = keys[p];
    int pos = atomicAdd(&offs[k], 1);
    float4 v;
    v.x = x[3 * p + 0]; v.y = x[3 * p + 1]; v.z = x[3 * p + 2];
    v.w = __int_as_float(p);
    sorted[pos] = v;
}

// Trilinear sample, border-zero semantics, channel-innermost vol, fused x-pair.
template<int C, int S>
__device__ __forceinline__ void trilerp(const float* __restrict__ vol,
                                        float cx, float cy, float cz,
                                        float* __restrict__ f) {
    const float hs = (float)S * 0.5f;
    float gx = fmaf(cx, hs, hs - 0.5f);
    float gy = fmaf(cy, hs, hs - 0.5f);
    float gz = fmaf(cz, hs, hs - 0.5f);
    float fx = floorf(gx), fy = floorf(gy), fz = floorf(gz);
    float tx = gx - fx, ty = gy - fy, tz = gz - fz;
    int x0 = (int)fx, y0 = (int)fy, z0 = (int)fz;
    // x0 in [-1, S-1]: corner0 valid iff x0>=0, corner1 valid iff x0+1<S.
    float wx0 = (1.f - tx) * ((x0 >= 0)    ? 1.f : 0.f);
    float wx1 = tx         * ((x0 + 1 < S) ? 1.f : 0.f);
    float wy0 = (1.f - ty) * ((y0 >= 0)    ? 1.f : 0.f);
    float wy1 = ty         * ((y0 + 1 < S) ? 1.f : 0.f);
    float wz0 = (1.f - tz) * ((z0 >= 0)    ? 1.f : 0.f);
    float wz1 = tz         * ((z0 + 1 < S) ? 1.f : 0.f);

    const int xb = max(x0, 0);            // fused-pair base (clamped-left edge)
    const bool xlo_ok = (x0 >= 0);
    int ys[2], zs[2];
    ys[0] = max(y0, 0); ys[1] = min(y0 + 1, S - 1);
    zs[0] = max(z0, 0); zs[1] = min(z0 + 1, S - 1);
    float wys[2] = {wy0, wy1}, wzs[2] = {wz0, wz1};

#pragma unroll
    for (int dz = 0; dz < 2; ++dz) {
#pragma unroll
        for (int dy = 0; dy < 2; ++dy) {
            const float wzy = wzs[dz] * wys[dy];
            const float w0 = wzy * wx0, w1 = wzy * wx1;
            const float* p = vol + ((zs[dz] * S + ys[dy]) * S + xb) * C;
            if (C == 4) {
                float4 lo = *reinterpret_cast<const float4*>(p);
                float4 hi = *reinterpret_cast<const float4*>(p + 4);
                if (!xlo_ok) hi = lo;  // corner1 value is clamped index 0
                f[0] = fmaf(w0, lo.x, f[0]); f[0] = fmaf(w1, hi.x, f[0]);
                f[1] = fmaf(w0, lo.y, f[1]); f[1] = fmaf(w1, hi.y, f[1]);
                f[2] = fmaf(w0, lo.z, f[2]); f[2] = fmaf(w1, hi.z, f[2]);
                f[3] = fmaf(w0, lo.w, f[3]); f[3] = fmaf(w1, hi.w, f[3]);
            } else {
                float4 v = *reinterpret_cast<const float4*>(p);
                float hx = xlo_ok ? v.z : v.x;
                float hy = xlo_ok ? v.w : v.y;
                f[0] = fmaf(w0, v.x, f[0]); f[0] = fmaf(w1, hx, f[0]);
                f[1] = fmaf(w0, v.y, f[1]); f[1] = fmaf(w1, hy, f[1]);
            }
        }
    }
}

__global__ __launch_bounds__(256)
void motion_grid_main(const float4* __restrict__ sorted,
                      const float* __restrict__ xraw,
                      const float* __restrict__ g0,
                      const float* __restrict__ g1,
                      const float* __restrict__ g2,
                      const float* __restrict__ w1,
                      const float* __restrict__ b1,
                      const float* __restrict__ w2,
                      const float* __restrict__ b2,
                      float* __restrict__ out, int npts, int sortedMode) {
    __shared__ float sW1[64 * 20];
    __shared__ float sB1[64];
    __shared__ float sW2[7 * 64];
    __shared__ float sB2[7];
    for (int i = threadIdx.x; i < 64 * 20; i += 256) sW1[i] = w1[i];
    for (int i = threadIdx.x; i < 7 * 64; i += 256) sW2[i] = w2[i];
    if (threadIdx.x < 64) sB1[threadIdx.x] = b1[threadIdx.x];
    if (threadIdx.x < 7) sB2[threadIdx.x] = b2[threadIdx.x];
    __syncthreads();

    const int p = blockIdx.x * 256 + threadIdx.x;
    if (p >= npts) return;

    float xv, yv, zv;
    int orig;
    if (sortedMode) {
        float4 sp = sorted[p];
        xv = sp.x; yv = sp.y; zv = sp.z; orig = __float_as_int(sp.w);
    } else {
        xv = xraw[3 * p + 0]; yv = xraw[3 * p + 1]; zv = xraw[3 * p + 2];
        orig = p;
    }

    // hw trig takes revolutions: sin(pi t)=hw(t/2), sin(2pi t)=hw(t), sin(4pi t)=hw(2t)
    float s1[3], c1[3], s2[3], c2[3], s4[3], c4[3];
    {
        const float xs[3] = {xv, yv, zv};
#pragma unroll
        for (int d = 0; d < 3; ++d) {
            s1[d] = __builtin_amdgcn_sinf(0.5f * xs[d]);
            c1[d] = __builtin_amdgcn_cosf(0.5f * xs[d]);
            s2[d] = __builtin_amdgcn_sinf(xs[d]);
            c2[d] = __builtin_amdgcn_cosf(xs[d]);
            s4[d] = __builtin_amdgcn_sinf(2.0f * xs[d]);
            c4[d] = __builtin_amdgcn_cosf(2.0f * xs[d]);
        }
    }

    float f[20];
#pragma unroll
    for (int i = 0; i < 20; ++i) f[i] = 0.f;

    trilerp<4, 32>(g0, s1[0], s1[1], s1[2], f + 0);
    trilerp<4, 32>(g0, c1[0], c1[1], c1[2], f + 4);
    trilerp<4, 64>(g1, s2[0], s2[1], s2[2], f + 8);
    trilerp<4, 64>(g1, c2[0], c2[1], c2[2], f + 12);
    trilerp<2, 128>(g2, s4[0], s4[1], s4[2], f + 16);
    trilerp<2, 128>(g2, c4[0], c4[1], c4[2], f + 18);

    float acc[7];
#pragma unroll
    for (int o = 0; o < 7; ++o) acc[o] = sB2[o];

#pragma unroll 4
    for (int j = 0; j < 64; ++j) {
        float s = sB1[j];
#pragma unroll
        for (int k = 0; k < 20; ++k) s = fmaf(f[k], sW1[j * 20 + k], s);
        float h = fmaxf(s, 0.01f * s);
#pragma unroll
        for (int o = 0; o < 7; ++o) acc[o] = fmaf(h, sW2[o * 64 + j], acc[o]);
    }

    float* op = out + (size_t)orig * 7;
#pragma unroll
    for (int o = 0; o < 7; ++o) op[o] = acc[o];
}

extern "C" void kernel_launch(void* const* d_in, const int* in_sizes, int n_in,
                              void* d_out, int out_size, void* d_ws, size_t ws_size,
                              hipStream_t stream) {
    const float* x  = (const float*)d_in[0];
    const float* g0 = (const float*)d_in[1];
    const float* g1 = (const float*)d_in[2];
    const float* g2 = (const float*)d_in[3];
    const float* n0 = (const float*)d_in[4];
    const float* n1 = (const float*)d_in[5];
    const float* n2 = (const float*)d_in[6];
    const float* w1 = (const float*)d_in[7];
    const float* b1 = (const float*)d_in[8];
    const float* w2 = (const float*)d_in[9];
    const float* b2 = (const float*)d_in[10];
    float* out = (float*)d_out;

    const int npts = in_sizes[0] / 3;

    // Workspace carve-up (aligned, with slack for fused-pair overreads).
    char* ws = (char*)d_ws;
    size_t cur = 0;
    auto alloc = [&](size_t bytes) {
        char* p = ws + cur;
        cur = (cur + bytes + 255) & ~(size_t)255;
        return p;
    };
    float*  p0     = (float*)alloc(32768u   * 4 * 4 + 64);
    float*  p1     = (float*)alloc(262144u  * 4 * 4 + 64);
    float*  p2     = (float*)alloc(2097152u * 2 * 4 + 64);
    int*    hist   = (int*)  alloc(NBINS * 4);
    int*    offs   = (int*)  alloc(NBINS * 4);
    int*    keys   = (int*)  alloc((size_t)npts * 4);
    float4* sorted = (float4*)alloc((size_t)npts * 16);
    const int useSorted = (ws_size >= cur) ? 1 : 0;

    pack_grid_k<4><<<(32768 + 255) / 256, 256, 0, stream>>>(g0, n0, p0, 32768);
    pack_grid_k<4><<<(262144 + 255) / 256, 256, 0, stream>>>(g1, n1, p1, 262144);
    pack_grid_k<2><<<(2097152 + 255) / 256, 256, 0, stream>>>(g2, n2, p2, 2097152);

    const int nblk = (npts + 255) / 256;
    if (useSorted) {
        hipMemsetAsync(hist, 0, NBINS * 4, stream);
        hist_k<<<nblk, 256, 0, stream>>>(x, keys, hist, npts);
        scan_k<<<1, 256, 0, stream>>>(hist, offs);
        scatter_k<<<nblk, 256, 0, stream>>>(x, keys, offs, sorted, npts);
    }

    motion_grid_main<<<nblk, 256, 0, stream>>>(
        sorted, x, p0, p1, p2, w1, b1, w2, b2, out, npts, useSorted);
}

// Round 3
// 476.001 us; speedup vs baseline: 1.4897x; 1.4897x over previous
//
#include <hip/hip_runtime.h>

// ---------------------------------------------------------------------------
// Motion_Grid: PE(sin/cos @ 3 freqs) -> 6 trilinear samples (3 grids) -> MLP
// Round 3: bucket-sort on RAW x (uniform -> no hot-bin atomics), scalar-pipe
//          weight loads (no LDS in main), fused x-corner-pair gathers.
// ---------------------------------------------------------------------------

#define NBINS 32768   // 32^3 buckets over raw x in [0,1)^3
#define NXCD 8

// Pack grid + noise into (D,H,W,C) layout so one corner-pair = contiguous bytes.
template<int C>
__global__ __launch_bounds__(256)
void pack_grid_k(const float* __restrict__ g, const float* __restrict__ nz,
                 float* __restrict__ out, int nvox) {
    int v = blockIdx.x * 256 + threadIdx.x;
    if (v >= nvox) return;
    float vals[C];
#pragma unroll
    for (int c = 0; c < C; ++c) vals[c] = g[c * nvox + v] + nz[c * nvox + v];
#pragma unroll
    for (int c = 0; c < C; ++c) out[v * C + c] = vals[c];
}

// w2t[j*8+o] = w2[o*64+j]  (row-contiguous per j, padded to 8 for s_load_x8)
__global__ __launch_bounds__(512)
void pack_w2t_k(const float* __restrict__ w2, float* __restrict__ w2t) {
    int i = threadIdx.x;
    int j = i >> 3, o = i & 7;
    w2t[i] = (o < 7) ? w2[o * 64 + j] : 0.f;
}

__device__ __forceinline__ int bin_of(float xv, float yv, float zv) {
    int qx = min(max((int)(xv * 32.f), 0), 31);
    int qy = min(max((int)(yv * 32.f), 0), 31);
    int qz = min(max((int)(zv * 32.f), 0), 31);
    return (qz << 10) | (qy << 5) | qx;   // x-fastest: consecutive bins adjacent in x
}

__global__ __launch_bounds__(256)
void hist_k(const float* __restrict__ x, int* __restrict__ hist, int npts) {
    int p = blockIdx.x * 256 + threadIdx.x;
    if (p >= npts) return;
    atomicAdd(&hist[bin_of(x[3 * p], x[3 * p + 1], x[3 * p + 2])], 1);
}

// Exclusive prefix sum over NBINS bins; one 1024-thread block.
__global__ __launch_bounds__(1024)
void scan_k(const int* __restrict__ hist, int* __restrict__ offs) {
    __shared__ int part[1024];
    const int PER = NBINS / 1024;  // 32
    int tid = threadIdx.x;
    int base = tid * PER;
    int s = 0;
#pragma unroll
    for (int i = 0; i < PER; ++i) s += hist[base + i];
    part[tid] = s;
    __syncthreads();
    // Hillis-Steele inclusive scan in LDS
    for (int d = 1; d < 1024; d <<= 1) {
        int v = (tid >= d) ? part[tid - d] : 0;
        __syncthreads();
        part[tid] += v;
        __syncthreads();
    }
    int run = (tid > 0) ? part[tid - 1] : 0;
    for (int i = 0; i < PER; ++i) { offs[base + i] = run; run += hist[base + i]; }
}

__global__ __launch_bounds__(256)
void scatter_k(const float* __restrict__ x, int* __restrict__ offs,
               float4* __restrict__ sorted, int npts) {
    int p = blockIdx.x * 256 + threadIdx.x;
    if (p >= npts) return;
    float xv = x[3 * p], yv = x[3 * p + 1], zv = x[3 * p + 2];
    int pos = atomicAdd(&offs[bin_of(xv, yv, zv)], 1);
    float4 v; v.x = xv; v.y = yv; v.z = zv; v.w = __int_as_float(p);
    sorted[pos] = v;
}

// Trilinear sample, border-zero semantics, channel-innermost vol, fused x-pair.
template<int C, int S>
__device__ __forceinline__ void trilerp(const float* __restrict__ vol,
                                        float cx, float cy, float cz,
                                        float* __restrict__ f) {
    const float hs = (float)S * 0.5f;
    float gx = fmaf(cx, hs, hs - 0.5f);
    float gy = fmaf(cy, hs, hs - 0.5f);
    float gz = fmaf(cz, hs, hs - 0.5f);
    float fx = floorf(gx), fy = floorf(gy), fz = floorf(gz);
    float tx = gx - fx, ty = gy - fy, tz = gz - fz;
    int x0 = (int)fx, y0 = (int)fy, z0 = (int)fz;
    float wx0 = (1.f - tx) * ((x0 >= 0)    ? 1.f : 0.f);
    float wx1 = tx         * ((x0 + 1 < S) ? 1.f : 0.f);
    float wy0 = (1.f - ty) * ((y0 >= 0)    ? 1.f : 0.f);
    float wy1 = ty         * ((y0 + 1 < S) ? 1.f : 0.f);
    float wz0 = (1.f - tz) * ((z0 >= 0)    ? 1.f : 0.f);
    float wz1 = tz         * ((z0 + 1 < S) ? 1.f : 0.f);

    const int xb = max(x0, 0);
    const bool xlo_ok = (x0 >= 0);
    int ys[2], zs[2];
    ys[0] = max(y0, 0); ys[1] = min(y0 + 1, S - 1);
    zs[0] = max(z0, 0); zs[1] = min(z0 + 1, S - 1);
    float wys[2] = {wy0, wy1}, wzs[2] = {wz0, wz1};

#pragma unroll
    for (int dz = 0; dz < 2; ++dz) {
#pragma unroll
        for (int dy = 0; dy < 2; ++dy) {
            const float wzy = wzs[dz] * wys[dy];
            const float w0 = wzy * wx0, w1 = wzy * wx1;
            const float* p = vol + ((zs[dz] * S + ys[dy]) * S + xb) * C;
            if (C == 4) {
                float4 lo = *reinterpret_cast<const float4*>(p);
                float4 hi = *reinterpret_cast<const float4*>(p + 4);
                if (!xlo_ok) hi = lo;
                f[0] = fmaf(w0, lo.x, f[0]); f[0] = fmaf(w1, hi.x, f[0]);
                f[1] = fmaf(w0, lo.y, f[1]); f[1] = fmaf(w1, hi.y, f[1]);
                f[2] = fmaf(w0, lo.z, f[2]); f[2] = fmaf(w1, hi.z, f[2]);
                f[3] = fmaf(w0, lo.w, f[3]); f[3] = fmaf(w1, hi.w, f[3]);
            } else {
                float4 v = *reinterpret_cast<const float4*>(p);
                float hx = xlo_ok ? v.z : v.x;
                float hy = xlo_ok ? v.w : v.y;
                f[0] = fmaf(w0, v.x, f[0]); f[0] = fmaf(w1, hx, f[0]);
                f[1] = fmaf(w0, v.y, f[1]); f[1] = fmaf(w1, hy, f[1]);
            }
        }
    }
}

__global__ __launch_bounds__(256)
void motion_grid_main(const float4* __restrict__ sorted,
                      const float* __restrict__ xraw,
                      const float* __restrict__ g0,
                      const float* __restrict__ g1,
                      const float* __restrict__ g2,
                      const float* __restrict__ w1,
                      const float* __restrict__ b1,
                      const float* __restrict__ w2t,
                      const float* __restrict__ b2,
                      float* __restrict__ out, int npts, int sortedMode,
                      int nblk) {
    // Chunked XCD swizzle: each XCD gets a contiguous run of sorted blocks.
    int bid = blockIdx.x;
    if ((nblk & (NXCD - 1)) == 0) {
        int cpx = nblk / NXCD;
        bid = (bid % NXCD) * cpx + bid / NXCD;
    }
    const int p = bid * 256 + threadIdx.x;
    if (p >= npts) return;

    float xv, yv, zv;
    int orig;
    if (sortedMode) {
        float4 sp = sorted[p];
        xv = sp.x; yv = sp.y; zv = sp.z; orig = __float_as_int(sp.w);
    } else {
        xv = xraw[3 * p]; yv = xraw[3 * p + 1]; zv = xraw[3 * p + 2];
        orig = p;
    }

    // hw trig takes revolutions: sin(pi t)=hw(t/2), sin(2pi t)=hw(t), sin(4pi t)=hw(2t)
    float s1[3], c1[3], s2[3], c2[3], s4[3], c4[3];
    {
        const float xs[3] = {xv, yv, zv};
#pragma unroll
        for (int d = 0; d < 3; ++d) {
            s1[d] = __builtin_amdgcn_sinf(0.5f * xs[d]);
            c1[d] = __builtin_amdgcn_cosf(0.5f * xs[d]);
            s2[d] = __builtin_amdgcn_sinf(xs[d]);
            c2[d] = __builtin_amdgcn_cosf(xs[d]);
            s4[d] = __builtin_amdgcn_sinf(2.0f * xs[d]);
            c4[d] = __builtin_amdgcn_cosf(2.0f * xs[d]);
        }
    }

    float f[20];
#pragma unroll
    for (int i = 0; i < 20; ++i) f[i] = 0.f;

    trilerp<4, 32>(g0, s1[0], s1[1], s1[2], f + 0);
    trilerp<4, 32>(g0, c1[0], c1[1], c1[2], f + 4);
    trilerp<4, 64>(g1, s2[0], s2[1], s2[2], f + 8);
    trilerp<4, 64>(g1, c2[0], c2[1], c2[2], f + 12);
    trilerp<2, 128>(g2, s4[0], s4[1], s4[2], f + 16);
    trilerp<2, 128>(g2, c4[0], c4[1], c4[2], f + 18);

    // MLP. Weights are wave-uniform: compile-time / loop-uniform indices off
    // kernel-arg pointers -> scalar (s_load) path, co-issues with VALU.
    float acc[7];
#pragma unroll
    for (int o = 0; o < 7; ++o) acc[o] = b2[o];

#pragma unroll 4
    for (int j = 0; j < 64; ++j) {
        float s = b1[j];
#pragma unroll
        for (int k = 0; k < 20; ++k) s = fmaf(f[k], w1[j * 20 + k], s);
        float h = fmaxf(s, 0.01f * s);
#pragma unroll
        for (int o = 0; o < 7; ++o) acc[o] = fmaf(h, w2t[j * 8 + o], acc[o]);
    }

    float* op = out + (size_t)orig * 7;
#pragma unroll
    for (int o = 0; o < 7; ++o) op[o] = acc[o];
}

extern "C" void kernel_launch(void* const* d_in, const int* in_sizes, int n_in,
                              void* d_out, int out_size, void* d_ws, size_t ws_size,
                              hipStream_t stream) {
    const float* x  = (const float*)d_in[0];
    const float* g0 = (const float*)d_in[1];
    const float* g1 = (const float*)d_in[2];
    const float* g2 = (const float*)d_in[3];
    const float* n0 = (const float*)d_in[4];
    const float* n1 = (const float*)d_in[5];
    const float* n2 = (const float*)d_in[6];
    const float* w1 = (const float*)d_in[7];
    const float* b1 = (const float*)d_in[8];
    const float* w2 = (const float*)d_in[9];
    const float* b2 = (const float*)d_in[10];
    float* out = (float*)d_out;

    const int npts = in_sizes[0] / 3;

    char* ws = (char*)d_ws;
    size_t cur = 0;
    auto alloc = [&](size_t bytes) {
        char* p = ws + cur;
        cur = (cur + bytes + 255) & ~(size_t)255;
        return p;
    };
    float*  p0     = (float*)alloc(32768u   * 4 * 4 + 64);
    float*  p1     = (float*)alloc(262144u  * 4 * 4 + 64);
    float*  p2     = (float*)alloc(2097152u * 2 * 4 + 64);
    float*  w2t    = (float*)alloc(512 * 4);
    int*    hist   = (int*)  alloc(NBINS * 4);
    int*    offs   = (int*)  alloc(NBINS * 4);
    float4* sorted = (float4*)alloc((size_t)npts * 16);
    const int useSorted = (ws_size >= cur) ? 1 : 0;

    pack_grid_k<4><<<(32768 + 255) / 256, 256, 0, stream>>>(g0, n0, p0, 32768);
    pack_grid_k<4><<<(262144 + 255) / 256, 256, 0, stream>>>(g1, n1, p1, 262144);
    pack_grid_k<2><<<(2097152 + 255) / 256, 256, 0, stream>>>(g2, n2, p2, 2097152);
    pack_w2t_k<<<1, 512, 0, stream>>>(w2, w2t);

    const int nblk = (npts + 255) / 256;
    if (useSorted) {
        hipMemsetAsync(hist, 0, NBINS * 4, stream);
        hist_k<<<nblk, 256, 0, stream>>>(x, hist, npts);
        scan_k<<<1, 1024, 0, stream>>>(hist, offs);
        scatter_k<<<nblk, 256, 0, stream>>>(x, offs, sorted, npts);
    }

    motion_grid_main<<<nblk, 256, 0, stream>>>(
        sorted, x, p0, p1, p2, w1, b1, w2t, b2, out, npts, useSorted, nblk);
}